// Round 2
// baseline (175.516 us; speedup 1.0000x reference)
//
#include <hip/hip_runtime.h>
#include <hip/hip_bf16.h>
#include <math.h>

// ---------------------------------------------------------------------------
// CrossAttention on MI355X (gfx950), bf16 MFMA pipeline, round 17
// (resubmission of R16 — two GPUAcquisitionTimeouts, never measured).
//   cast_all: fp32 -> bf16 (BW-bound pass)
//   proj_qkv: 128x128, BK=64, coalesced 4-lane/row staging (R12/R14)
//   attn: R15 structure (BQ=256, 512-thread blocks, 8 waves share K/V tile)
//         + R16: register-prefetch pipeline for K/V staging (same pattern as
//           gemm_body: prologue load, in-loop prefetch after 2nd barrier) so
//           global-load latency hides under chunk compute, and
//           s_setprio(1/0) around the QK / PV MFMA clusters (T5).
//   gemm_out: 64x128, BK=64, combine in staging, inv hoisted (R12/R14)
// ---------------------------------------------------------------------------

typedef __bf16 bf16x8 __attribute__((ext_vector_type(8)));
typedef __bf16 bf16x4 __attribute__((ext_vector_type(4)));
typedef float f32x4 __attribute__((ext_vector_type(4)));

#define QSCALE 0.18033688011112042f  // 0.125 * log2(e)

#if __has_builtin(__builtin_amdgcn_exp2f)
#define EXP2(x) __builtin_amdgcn_exp2f(x)
#else
#define EXP2(x) exp2f(x)
#endif

__device__ __forceinline__ f32x4 mfma32(bf16x8 a, bf16x8 b, f32x4 c) {
  // 16x16x32: A[m=ln][k=qd*8+j], B[n=ln][k=qd*8+j].
  // D: A's m -> (qd*4+rg), B's n -> ln.
  return __builtin_amdgcn_mfma_f32_16x16x32_bf16(a, b, c, 0, 0, 0);
}

// ---------------------------------------------------------------------------
// fp32 -> bf16 cast of all inputs.
// ---------------------------------------------------------------------------
__global__ __launch_bounds__(256) void cast_all(
    const float* __restrict__ x, const float* __restrict__ ctx,
    const float* __restrict__ wq, const float* __restrict__ wk,
    const float* __restrict__ wv, const float* __restrict__ wo,
    __bf16* __restrict__ xb, __bf16* __restrict__ cb,
    __bf16* __restrict__ wqb, __bf16* __restrict__ wkb,
    __bf16* __restrict__ wvb, __bf16* __restrict__ wob) {
  const int B0 = 1048576;
  const int B1 = 2621440;
  const int B2 = 2686976;
  const int B3 = 2785280;
  const int B4 = 2883584;
  const int B5 = 2949120;
  for (int i = blockIdx.x * blockDim.x + threadIdx.x; i < B5;
       i += gridDim.x * blockDim.x) {
    const float* s;
    __bf16* d;
    int off;
    if (i < B0)      { s = x;   d = xb;  off = i; }
    else if (i < B1) { s = ctx; d = cb;  off = i - B0; }
    else if (i < B2) { s = wq;  d = wqb; off = i - B1; }
    else if (i < B3) { s = wk;  d = wkb; off = i - B2; }
    else if (i < B4) { s = wv;  d = wvb; off = i - B3; }
    else             { s = wo;  d = wob; off = i - B4; }
    float4 f = ((const float4*)s)[off];
    union { __bf16 b[4]; ushort4 u; } cv;
    cv.b[0] = (__bf16)f.x; cv.b[1] = (__bf16)f.y;
    cv.b[2] = (__bf16)f.z; cv.b[3] = (__bf16)f.w;
    ((ushort4*)d)[off] = cv.u;
  }
}

// ---------------------------------------------------------------------------
// 128x128 GEMM body, BK=64, register-prefetch pipeline, coalesced staging.
// MODE 0 (roles swapped): bf16 out [b,h,tok,d], 8B stores over d
// MODE 1 (natural roles): bf16 out [b,h,d,tok], 8B stores over tok
// ---------------------------------------------------------------------------
template <int MODE>
__device__ __forceinline__ void gemm_body(
    const __bf16* __restrict__ A, const __bf16* __restrict__ W,
    __bf16* __restrict__ Cout, int Kd, float scale, int m0, int n0,
    __bf16 (*As)[72], __bf16 (*Bs)[72]) {
  const int t = threadIdx.x;
  const int w = t >> 6;
  const int lane = t & 63;
  const int ln = lane & 15;
  const int qd = lane >> 4;
  const int wm = (w >> 1) * 64;
  const int wn = (w & 1) * 64;

  f32x4 zero4 = {0.f, 0.f, 0.f, 0.f};
  f32x4 acc[4][4];
#pragma unroll
  for (int i = 0; i < 4; ++i)
#pragma unroll
    for (int j = 0; j < 4; ++j) acc[i][j] = zero4;

  const int r0 = t >> 2;          // 0..63
  const int c0 = (t & 3) * 16;    // 0/16/32/48
  const __bf16* gA0 = A + (size_t)(m0 + r0) * Kd + c0;
  const __bf16* gA1 = A + (size_t)(m0 + r0 + 64) * Kd + c0;
  const __bf16* gB0 = W + (size_t)(n0 + r0) * Kd + c0;
  const __bf16* gB1 = W + (size_t)(n0 + r0 + 64) * Kd + c0;

  // prologue: load tile 0 into registers
  uint4 a00 = *(const uint4*)gA0, a01 = *(const uint4*)(gA0 + 8);
  uint4 a10 = *(const uint4*)gA1, a11 = *(const uint4*)(gA1 + 8);
  uint4 b00 = *(const uint4*)gB0, b01 = *(const uint4*)(gB0 + 8);
  uint4 b10 = *(const uint4*)gB1, b11 = *(const uint4*)(gB1 + 8);

  for (int kc = 0; kc < Kd; kc += 64) {
    __syncthreads();  // previous iteration's frag reads complete
    *(uint4*)&As[r0][c0] = a00;       *(uint4*)&As[r0][c0 + 8] = a01;
    *(uint4*)&As[r0 + 64][c0] = a10;  *(uint4*)&As[r0 + 64][c0 + 8] = a11;
    *(uint4*)&Bs[r0][c0] = b00;       *(uint4*)&Bs[r0][c0 + 8] = b01;
    *(uint4*)&Bs[r0 + 64][c0] = b10;  *(uint4*)&Bs[r0 + 64][c0 + 8] = b11;
    __syncthreads();  // LDS tile ready
    if (kc + 64 < Kd) {  // prefetch next tile: latency hidden behind MFMAs
      a00 = *(const uint4*)(gA0 + kc + 64);
      a01 = *(const uint4*)(gA0 + kc + 72);
      a10 = *(const uint4*)(gA1 + kc + 64);
      a11 = *(const uint4*)(gA1 + kc + 72);
      b00 = *(const uint4*)(gB0 + kc + 64);
      b01 = *(const uint4*)(gB0 + kc + 72);
      b10 = *(const uint4*)(gB1 + kc + 64);
      b11 = *(const uint4*)(gB1 + kc + 72);
    }
#pragma unroll
    for (int kst = 0; kst < 2; ++kst) {
      bf16x8 af[4], bfr[4];
#pragma unroll
      for (int i = 0; i < 4; ++i) {
        af[i] = *(const bf16x8*)&As[wm + i * 16 + ln][kst * 32 + qd * 8];
        bfr[i] = *(const bf16x8*)&Bs[wn + i * 16 + ln][kst * 32 + qd * 8];
      }
#pragma unroll
      for (int i = 0; i < 4; ++i)
#pragma unroll
        for (int j = 0; j < 4; ++j) {
          if (MODE == 1)
            acc[i][j] = mfma32(af[i], bfr[j], acc[i][j]);  // tok->(qd,rg)
          else
            acc[i][j] = mfma32(bfr[j], af[i], acc[i][j]);  // e->(qd,rg)
        }
    }
  }

#pragma unroll
  for (int i = 0; i < 4; ++i)
#pragma unroll
    for (int j = 0; j < 4; ++j) {
      if (MODE == 0) {
        const int gm = m0 + wm + i * 16 + ln;           // token
        const int gn0 = n0 + wn + j * 16 + qd * 4;      // e (4 consecutive)
        const int bb = gm >> 11, tok = gm & 2047;
        const int hh = gn0 >> 6, dd0 = gn0 & 63;
        bf16x4 v;
#pragma unroll
        for (int rg = 0; rg < 4; ++rg) v[rg] = (__bf16)(acc[i][j][rg] * scale);
        *(bf16x4*)(Cout + (((size_t)bb * 8 + hh) * 2048 + tok) * 64 + dd0) = v;
      } else {
        const int gm0 = m0 + wm + i * 16 + qd * 4;      // token (4 consecutive)
        const int gn = n0 + wn + j * 16 + ln;           // e
        const int bb = gm0 >> 11, tok0 = gm0 & 2047;
        const int hh = gn >> 6, dd = gn & 63;
        bf16x4 v;
#pragma unroll
        for (int rg = 0; rg < 4; ++rg) v[rg] = (__bf16)acc[i][j][rg];
        *(bf16x4*)(Cout + (((size_t)bb * 8 + hh) * 64 + dd) * 2048 + tok0) = v;
      }
    }
}

// Fused Q/K/V projections: grid (64, 12) = 768 blocks -> 3 blocks/CU.
__global__ __launch_bounds__(256, 3) void proj_qkv(
    const __bf16* __restrict__ xb, const __bf16* __restrict__ cb,
    const __bf16* __restrict__ Wq, const __bf16* __restrict__ Wk,
    const __bf16* __restrict__ Wv, __bf16* __restrict__ Qw,
    __bf16* __restrict__ Kw, __bf16* __restrict__ Vtw) {
  __shared__ __align__(16) __bf16 As[128][72];  // 18432B
  __shared__ __align__(16) __bf16 Bs[128][72];  // 18432B -> 36.9KB
  const int m0 = blockIdx.x * 128;
  const int job = blockIdx.y >> 2;  // 0=Q, 1=K, 2=V
  const int n0 = (blockIdx.y & 3) * 128;
  if (job == 0)
    gemm_body<0>(xb, Wq, Qw, 512, QSCALE, m0, n0, As, Bs);
  else if (job == 1)
    gemm_body<0>(cb, Wk, Kw, 768, 1.0f, m0, n0, As, Bs);
  else
    gemm_body<1>(cb, Wv, Vtw, 768, 1.0f, m0, n0, As, Bs);
}

// ---------------------------------------------------------------------------
// Final GEMM: out = ((O0+O1)/(l0+l1)) Wo^T + bo, fp32.  64x128 tile, BK=64,
// register-prefetch pipeline, grid (128,4)=512.  inv(l) hoisted.
// ---------------------------------------------------------------------------
__global__ __launch_bounds__(256) void gemm_out(
    const __bf16* __restrict__ O0, const __bf16* __restrict__ O1,
    const float* __restrict__ lbuf,  // [2][32][2048]
    const __bf16* __restrict__ B,    // Wo bf16 [512 x 512]
    float* __restrict__ C, const float* __restrict__ bias) {
  const int m0 = blockIdx.x * 64;
  const int n0 = blockIdx.y * 128;
  const int t = threadIdx.x;
  const int w = t >> 6;
  const int lane = t & 63;
  const int ln = lane & 15;
  const int qd = lane >> 4;
  const int wm = (w >> 1) * 32;
  const int wn = (w & 1) * 64;

  __shared__ __align__(16) __bf16 As[64][72];   //  9216B
  __shared__ __align__(16) __bf16 Bs[128][72];  // 18432B -> 27.6KB

  f32x4 zero4 = {0.f, 0.f, 0.f, 0.f};
  f32x4 acc[2][4];
#pragma unroll
  for (int i = 0; i < 2; ++i)
#pragma unroll
    for (int j = 0; j < 4; ++j) acc[i][j] = zero4;

  const int r0 = t >> 2;        // 0..63
  const int c0 = (t & 3) * 16;  // 0/16/32/48
  const int gm_s = m0 + r0;
  const int bidx = gm_s >> 11, tok_s = gm_s & 2047;
  const size_t aoff = (size_t)gm_s * 512 + c0;
  const __bf16* gB0 = B + (size_t)(n0 + r0) * 512 + c0;
  const __bf16* gB1 = B + (size_t)(n0 + r0 + 64) * 512 + c0;

  float inv[8];
#pragma unroll
  for (int hh = 0; hh < 8; ++hh) {
    const float l0 = lbuf[((size_t)bidx * 8 + hh) * 2048 + tok_s];
    const float l1 = lbuf[65536 + ((size_t)bidx * 8 + hh) * 2048 + tok_s];
    inv[hh] = 1.0f / (l0 + l1);
  }

  // prologue: load tile 0
  uint4 o00 = *(const uint4*)(O0 + aoff), o01 = *(const uint4*)(O0 + aoff + 8);
  uint4 o10 = *(const uint4*)(O1 + aoff), o11 = *(const uint4*)(O1 + aoff + 8);
  uint4 b00 = *(const uint4*)gB0, b01 = *(const uint4*)(gB0 + 8);
  uint4 b10 = *(const uint4*)gB1, b11 = *(const uint4*)(gB1 + 8);

  for (int kc = 0; kc < 512; kc += 64) {
    const float iv = inv[kc >> 6];
    union { bf16x8 v; uint4 u; } u0, u1, r0v, r1v;
    u0.u = o00; u1.u = o10;
#pragma unroll
    for (int e = 0; e < 8; ++e)
      r0v.v[e] = (__bf16)(((float)u0.v[e] + (float)u1.v[e]) * iv);
    u0.u = o01; u1.u = o11;
#pragma unroll
    for (int e = 0; e < 8; ++e)
      r1v.v[e] = (__bf16)(((float)u0.v[e] + (float)u1.v[e]) * iv);
    __syncthreads();
    *(uint4*)&As[r0][c0] = r0v.u;
    *(uint4*)&As[r0][c0 + 8] = r1v.u;
    *(uint4*)&Bs[r0][c0] = b00;       *(uint4*)&Bs[r0][c0 + 8] = b01;
    *(uint4*)&Bs[r0 + 64][c0] = b10;  *(uint4*)&Bs[r0 + 64][c0 + 8] = b11;
    __syncthreads();
    if (kc + 64 < 512) {
      o00 = *(const uint4*)(O0 + aoff + kc + 64);
      o01 = *(const uint4*)(O0 + aoff + kc + 72);
      o10 = *(const uint4*)(O1 + aoff + kc + 64);
      o11 = *(const uint4*)(O1 + aoff + kc + 72);
      b00 = *(const uint4*)(gB0 + kc + 64);
      b01 = *(const uint4*)(gB0 + kc + 72);
      b10 = *(const uint4*)(gB1 + kc + 64);
      b11 = *(const uint4*)(gB1 + kc + 72);
    }
#pragma unroll
    for (int kst = 0; kst < 2; ++kst) {
      bf16x8 af[2], bfr[4];
#pragma unroll
      for (int i = 0; i < 2; ++i)
        af[i] = *(const bf16x8*)&As[wm + i * 16 + ln][kst * 32 + qd * 8];
#pragma unroll
      for (int j = 0; j < 4; ++j)
        bfr[j] = *(const bf16x8*)&Bs[wn + j * 16 + ln][kst * 32 + qd * 8];
#pragma unroll
      for (int i = 0; i < 2; ++i)
#pragma unroll
        for (int j = 0; j < 4; ++j)
          acc[i][j] = mfma32(bfr[j], af[i], acc[i][j]);  // e->(qd,rg)
    }
  }

#pragma unroll
  for (int i = 0; i < 2; ++i)
#pragma unroll
    for (int j = 0; j < 4; ++j) {
      const int gm = m0 + wm + i * 16 + ln;
      const int gn0 = n0 + wn + j * 16 + qd * 4;
      f32x4 bi = *(const f32x4*)&bias[gn0];
      f32x4 v = acc[i][j] + bi;
      *(f32x4*)&C[(size_t)gm * 512 + gn0] = v;
    }
}

// ---------------------------------------------------------------------------
// Flash attention: S^T trick, raw-exp2 max-free softmax, split-K=2, Q in
// regs, sigma-permuted K rows -> x32 PV, ones-x32 l row-sum, Vs[64][136].
// R15: BQ=256 with 512-thread blocks (8 waves), grid (8,32,2) -> 2 blocks/CU.
// R16: register-prefetch pipeline for K/V staging (prologue load tile 0;
//      in-loop prefetch tile kt+1 right after the post-staging barrier so
//      ~200-900cyc global latency hides under the 4-chunk compute), plus
//      s_setprio(1/0) wrapped around the QK and PV MFMA clusters (T5).
// ---------------------------------------------------------------------------
__global__ __launch_bounds__(512, 4) void attn_kernel(
    const __bf16* __restrict__ Q,   // [BH][2048][64], pre-scaled by QSCALE
    const __bf16* __restrict__ K,   // [BH][2048][64]
    const __bf16* __restrict__ Vt,  // [BH][64][2048]
    __bf16* __restrict__ Oh,        // [2][B][2048][512] unnormalized
    float* __restrict__ lbuf) {     // [2][BH][2048]
  const int S = 2048;
  const int qt = blockIdx.x;  // 8 Q tiles of 256 rows
  const int bh = blockIdx.y;
  const int sp = blockIdx.z;
  const int b = bh >> 3, h = bh & 7;
  const int t = threadIdx.x;
  const int w = t >> 6;       // 0..7: wave owns Q rows qt*256 + w*32 ..
  const int lane = t & 63;
  const int ln = lane & 15;
  const int qd = lane >> 4;

  __shared__ __align__(16) __bf16 Ks[128][72];   // 18432B
  __shared__ __align__(16) __bf16 Vs[64][136];   // 17408B  total 35840B

  bf16x8 bq[2][2];  // [mt][kst]
  {
    const __bf16* qb =
        Q + ((size_t)bh * S + qt * 256 + w * 32 + ln) * 64 + qd * 8;
#pragma unroll
    for (int mt = 0; mt < 2; ++mt)
#pragma unroll
      for (int kst = 0; kst < 2; ++kst)
        bq[mt][kst] = *(const bf16x8*)(qb + mt * 1024 + kst * 32);
  }

  f32x4 zero4 = {0.f, 0.f, 0.f, 0.f};
  f32x4 o[2][4];
  f32x4 o_l[2];
#pragma unroll
  for (int mt = 0; mt < 2; ++mt) {
#pragma unroll
    for (int i = 0; i < 4; ++i) o[mt][i] = zero4;
    o_l[mt] = zero4;
  }
  bf16x8 ones8;
  {
    union { unsigned short u[8]; bf16x8 v; } U;
#pragma unroll
    for (int e = 0; e < 8; ++e) U.u[e] = 0x3F80;  // bf16 1.0
    ones8 = U.v;
  }

  // K staging: 512 threads, token row kr = t>>2 (0..127), 16 cols each
  const int kr = t >> 2, kc0 = (t & 3) * 16;
  // sigma: token v -> row 16*((v>>2)&1) + 4*(v>>3) + (v&3) within 32-chunk
  const int krow =
      (kr & ~31) | ((kr & 4) << 2) | (((kr >> 3) & 3) << 2) | (kr & 3);
  // V staging: d-row vd = t>>3 (0..63), 16 tokens each
  const int vd = t >> 3, vtok0 = (t & 7) * 16;
  const int kt0 = sp * 8;

  // Hoisted global staging bases (advance by constants per tile).
  const __bf16* gKbase = K + ((size_t)bh * S + kt0 * 128 + kr) * 64 + kc0;
  const __bf16* gVbase = Vt + ((size_t)bh * 64 + vd) * S + kt0 * 128 + vtok0;

  // prologue: load tile kt0 into registers
  uint4 kv0 = ((const uint4*)gKbase)[0], kv1 = ((const uint4*)gKbase)[1];
  uint4 vv0 = ((const uint4*)gVbase)[0], vv1 = ((const uint4*)gVbase)[1];

  for (int it = 0; it < 8; ++it) {
    __syncthreads();  // previous tile's frag reads complete
    {
      uint4* dK = (uint4*)&Ks[krow][kc0];    // 144B stride: 16B-aligned
      dK[0] = kv0; dK[1] = kv1;
      uint4* dV = (uint4*)&Vs[vd][vtok0];    // 272B stride: 16B-aligned
      dV[0] = vv0; dV[1] = vv1;
    }
    __syncthreads();  // LDS tile ready
    if (it + 1 < 8) {  // prefetch next K/V tile: hidden behind chunk compute
      const uint4* gK = (const uint4*)(gKbase + (size_t)(it + 1) * 128 * 64);
      const uint4* gV = (const uint4*)(gVbase + (size_t)(it + 1) * 128);
      kv0 = gK[0]; kv1 = gK[1];
      vv0 = gV[0]; vv1 = gV[1];
    }

    // per 32-token chunk c: QK (2 tiles) -> exp2 -> x32 PV + ones row-sum
#pragma unroll
    for (int c = 0; c < 4; ++c) {
      f32x4 s[2][2];  // [e][mt]
      s[0][0] = zero4; s[0][1] = zero4; s[1][0] = zero4; s[1][1] = zero4;
      __builtin_amdgcn_s_setprio(1);
#pragma unroll
      for (int e = 0; e < 2; ++e) {
        const int nt = c * 2 + e;
#pragma unroll
        for (int kst = 0; kst < 2; ++kst) {
          bf16x8 ak = *(const bf16x8*)&Ks[nt * 16 + ln][kst * 32 + qd * 8];
          s[e][0] = mfma32(ak, bq[0][kst], s[e][0]);
          s[e][1] = mfma32(ak, bq[1][kst], s[e][1]);
        }
      }
      __builtin_amdgcn_s_setprio(0);
#pragma unroll
      for (int e = 0; e < 2; ++e)
#pragma unroll
        for (int mt = 0; mt < 2; ++mt)
#pragma unroll
          for (int rg = 0; rg < 4; ++rg) s[e][mt][rg] = EXP2(s[e][mt][rg]);
      // pack P as x32 B-frag: lane holds tokens c*32 + qd*8 + j
      bf16x8 p[2];
#pragma unroll
      for (int mt = 0; mt < 2; ++mt) {
#pragma unroll
        for (int rg = 0; rg < 4; ++rg) {
          p[mt][rg] = (__bf16)s[0][mt][rg];
          p[mt][rg + 4] = (__bf16)s[1][mt][rg];
        }
      }
      __builtin_amdgcn_s_setprio(1);
      o_l[0] = mfma32(ones8, p[0], o_l[0]);
      o_l[1] = mfma32(ones8, p[1], o_l[1]);
#pragma unroll
      for (int i = 0; i < 4; ++i) {
        bf16x8 av = *(const bf16x8*)&Vs[i * 16 + ln][c * 32 + qd * 8];
        o[0][i] = mfma32(av, p[0], o[0][i]);
        o[1][i] = mfma32(av, p[1], o[1][i]);
      }
      __builtin_amdgcn_s_setprio(0);
    }
  }

  // ---- epilogue: write UNNORMALIZED O + l (combine happens in gemm_out)
  __bf16* Osp = Oh + (size_t)sp * 8192 * 512;
#pragma unroll
  for (int mt = 0; mt < 2; ++mt) {
    const int tok = qt * 256 + w * 32 + mt * 16 + ln;
    if (qd == 0) lbuf[((size_t)sp * 32 + bh) * 2048 + tok] = o_l[mt][0];
#pragma unroll
    for (int i = 0; i < 4; ++i) {
      bf16x4 v;
#pragma unroll
      for (int rg = 0; rg < 4; ++rg) v[rg] = (__bf16)o[mt][i][rg];
      const int col = h * 64 + i * 16 + qd * 4;
      *(bf16x4*)&Osp[((size_t)b * S + tok) * 512 + col] = v;
    }
  }
}

// ---------------------------------------------------------------------------
extern "C" void kernel_launch(void* const* d_in, const int* in_sizes, int n_in,
                              void* d_out, int out_size, void* d_ws,
                              size_t ws_size, hipStream_t stream) {
  const float* x = (const float*)d_in[0];
  const float* ctx = (const float*)d_in[1];
  const float* Wq = (const float*)d_in[2];
  const float* Wk = (const float*)d_in[3];
  const float* Wv = (const float*)d_in[4];
  const float* Wo = (const float*)d_in[5];
  const float* bo = (const float*)d_in[6];

  char* p = (char*)d_ws;
  __bf16* xb = (__bf16*)p;   p += (size_t)8192 * 512 * 2;
  __bf16* cb = (__bf16*)p;   p += (size_t)8192 * 768 * 2;
  __bf16* wqb = (__bf16*)p;  p += (size_t)512 * 512 * 2;
  __bf16* wkb = (__bf16*)p;  p += (size_t)512 * 768 * 2;
  __bf16* wvb = (__bf16*)p;  p += (size_t)512 * 768 * 2;
  __bf16* wob = (__bf16*)p;  p += (size_t)512 * 512 * 2;
  __bf16* Qw = (__bf16*)p;   p += (size_t)8192 * 512 * 2;
  __bf16* Kw = (__bf16*)p;   p += (size_t)8192 * 512 * 2;
  __bf16* Vtw = (__bf16*)p;  p += (size_t)8192 * 512 * 2;
  __bf16* Oh = (__bf16*)p;   p += (size_t)2 * 8192 * 512 * 2;
  float* lbuf = (float*)p;   p += (size_t)2 * 32 * 2048 * 4;

  cast_all<<<2880, 256, 0, stream>>>(x, ctx, Wq, Wk, Wv, Wo, xb, cb, wqb, wkb,
                                     wvb, wob);

  dim3 gp(64, 12);
  proj_qkv<<<gp, 256, 0, stream>>>(xb, cb, wqb, wkb, wvb, Qw, Kw, Vtw);

  dim3 ga(8, 32, 2);
  attn_kernel<<<ga, 512, 0, stream>>>(Qw, Kw, Vtw, Oh, lbuf);

  dim3 go(128, 4);
  gemm_out<<<go, 256, 0, stream>>>(Oh, Oh + (size_t)8192 * 512, lbuf, wob,
                                   (float*)d_out, bo);
}

// Round 3
// 174.681 us; speedup vs baseline: 1.0048x; 1.0048x over previous
//
#include <hip/hip_runtime.h>
#include <hip/hip_bf16.h>
#include <math.h>

// ---------------------------------------------------------------------------
// CrossAttention on MI355X (gfx950), bf16 MFMA pipeline, round 18.
//   cast_all: fp32 -> bf16 (BW-bound pass)
//   proj_qkv: 128x128, BK=64, coalesced 4-lane/row staging (R12/R14)
//   attn: R15 structure (BQ=256, 512-thread blocks, 8 waves share K/V tile)
//         R16: register-prefetch of next K/V tile + setprio on MFMA clusters
//         R18: LDS DOUBLE-BUFFER, single barrier per tile (T3 "minimum
//              2-phase"): ds_write of tile it+1 overlaps MFMAs on tile it;
//              global prefetch now runs a full iteration ahead.
//   gemm_out: 64x128, BK=64, combine in staging, inv hoisted (R12/R14)
// ---------------------------------------------------------------------------

typedef __bf16 bf16x8 __attribute__((ext_vector_type(8)));
typedef __bf16 bf16x4 __attribute__((ext_vector_type(4)));
typedef float f32x4 __attribute__((ext_vector_type(4)));

#define QSCALE 0.18033688011112042f  // 0.125 * log2(e)

#if __has_builtin(__builtin_amdgcn_exp2f)
#define EXP2(x) __builtin_amdgcn_exp2f(x)
#else
#define EXP2(x) exp2f(x)
#endif

__device__ __forceinline__ f32x4 mfma32(bf16x8 a, bf16x8 b, f32x4 c) {
  // 16x16x32: A[m=ln][k=qd*8+j], B[n=ln][k=qd*8+j].
  // D: A's m -> (qd*4+rg), B's n -> ln.
  return __builtin_amdgcn_mfma_f32_16x16x32_bf16(a, b, c, 0, 0, 0);
}

// ---------------------------------------------------------------------------
// fp32 -> bf16 cast of all inputs.
// ---------------------------------------------------------------------------
__global__ __launch_bounds__(256) void cast_all(
    const float* __restrict__ x, const float* __restrict__ ctx,
    const float* __restrict__ wq, const float* __restrict__ wk,
    const float* __restrict__ wv, const float* __restrict__ wo,
    __bf16* __restrict__ xb, __bf16* __restrict__ cb,
    __bf16* __restrict__ wqb, __bf16* __restrict__ wkb,
    __bf16* __restrict__ wvb, __bf16* __restrict__ wob) {
  const int B0 = 1048576;
  const int B1 = 2621440;
  const int B2 = 2686976;
  const int B3 = 2785280;
  const int B4 = 2883584;
  const int B5 = 2949120;
  for (int i = blockIdx.x * blockDim.x + threadIdx.x; i < B5;
       i += gridDim.x * blockDim.x) {
    const float* s;
    __bf16* d;
    int off;
    if (i < B0)      { s = x;   d = xb;  off = i; }
    else if (i < B1) { s = ctx; d = cb;  off = i - B0; }
    else if (i < B2) { s = wq;  d = wqb; off = i - B1; }
    else if (i < B3) { s = wk;  d = wkb; off = i - B2; }
    else if (i < B4) { s = wv;  d = wvb; off = i - B3; }
    else             { s = wo;  d = wob; off = i - B4; }
    float4 f = ((const float4*)s)[off];
    union { __bf16 b[4]; ushort4 u; } cv;
    cv.b[0] = (__bf16)f.x; cv.b[1] = (__bf16)f.y;
    cv.b[2] = (__bf16)f.z; cv.b[3] = (__bf16)f.w;
    ((ushort4*)d)[off] = cv.u;
  }
}

// ---------------------------------------------------------------------------
// 128x128 GEMM body, BK=64, register-prefetch pipeline, coalesced staging.
// MODE 0 (roles swapped): bf16 out [b,h,tok,d], 8B stores over d
// MODE 1 (natural roles): bf16 out [b,h,d,tok], 8B stores over tok
// ---------------------------------------------------------------------------
template <int MODE>
__device__ __forceinline__ void gemm_body(
    const __bf16* __restrict__ A, const __bf16* __restrict__ W,
    __bf16* __restrict__ Cout, int Kd, float scale, int m0, int n0,
    __bf16 (*As)[72], __bf16 (*Bs)[72]) {
  const int t = threadIdx.x;
  const int w = t >> 6;
  const int lane = t & 63;
  const int ln = lane & 15;
  const int qd = lane >> 4;
  const int wm = (w >> 1) * 64;
  const int wn = (w & 1) * 64;

  f32x4 zero4 = {0.f, 0.f, 0.f, 0.f};
  f32x4 acc[4][4];
#pragma unroll
  for (int i = 0; i < 4; ++i)
#pragma unroll
    for (int j = 0; j < 4; ++j) acc[i][j] = zero4;

  const int r0 = t >> 2;          // 0..63
  const int c0 = (t & 3) * 16;    // 0/16/32/48
  const __bf16* gA0 = A + (size_t)(m0 + r0) * Kd + c0;
  const __bf16* gA1 = A + (size_t)(m0 + r0 + 64) * Kd + c0;
  const __bf16* gB0 = W + (size_t)(n0 + r0) * Kd + c0;
  const __bf16* gB1 = W + (size_t)(n0 + r0 + 64) * Kd + c0;

  // prologue: load tile 0 into registers
  uint4 a00 = *(const uint4*)gA0, a01 = *(const uint4*)(gA0 + 8);
  uint4 a10 = *(const uint4*)gA1, a11 = *(const uint4*)(gA1 + 8);
  uint4 b00 = *(const uint4*)gB0, b01 = *(const uint4*)(gB0 + 8);
  uint4 b10 = *(const uint4*)gB1, b11 = *(const uint4*)(gB1 + 8);

  for (int kc = 0; kc < Kd; kc += 64) {
    __syncthreads();  // previous iteration's frag reads complete
    *(uint4*)&As[r0][c0] = a00;       *(uint4*)&As[r0][c0 + 8] = a01;
    *(uint4*)&As[r0 + 64][c0] = a10;  *(uint4*)&As[r0 + 64][c0 + 8] = a11;
    *(uint4*)&Bs[r0][c0] = b00;       *(uint4*)&Bs[r0][c0 + 8] = b01;
    *(uint4*)&Bs[r0 + 64][c0] = b10;  *(uint4*)&Bs[r0 + 64][c0 + 8] = b11;
    __syncthreads();  // LDS tile ready
    if (kc + 64 < Kd) {  // prefetch next tile: latency hidden behind MFMAs
      a00 = *(const uint4*)(gA0 + kc + 64);
      a01 = *(const uint4*)(gA0 + kc + 72);
      a10 = *(const uint4*)(gA1 + kc + 64);
      a11 = *(const uint4*)(gA1 + kc + 72);
      b00 = *(const uint4*)(gB0 + kc + 64);
      b01 = *(const uint4*)(gB0 + kc + 72);
      b10 = *(const uint4*)(gB1 + kc + 64);
      b11 = *(const uint4*)(gB1 + kc + 72);
    }
#pragma unroll
    for (int kst = 0; kst < 2; ++kst) {
      bf16x8 af[4], bfr[4];
#pragma unroll
      for (int i = 0; i < 4; ++i) {
        af[i] = *(const bf16x8*)&As[wm + i * 16 + ln][kst * 32 + qd * 8];
        bfr[i] = *(const bf16x8*)&Bs[wn + i * 16 + ln][kst * 32 + qd * 8];
      }
#pragma unroll
      for (int i = 0; i < 4; ++i)
#pragma unroll
        for (int j = 0; j < 4; ++j) {
          if (MODE == 1)
            acc[i][j] = mfma32(af[i], bfr[j], acc[i][j]);  // tok->(qd,rg)
          else
            acc[i][j] = mfma32(bfr[j], af[i], acc[i][j]);  // e->(qd,rg)
        }
    }
  }

#pragma unroll
  for (int i = 0; i < 4; ++i)
#pragma unroll
    for (int j = 0; j < 4; ++j) {
      if (MODE == 0) {
        const int gm = m0 + wm + i * 16 + ln;           // token
        const int gn0 = n0 + wn + j * 16 + qd * 4;      // e (4 consecutive)
        const int bb = gm >> 11, tok = gm & 2047;
        const int hh = gn0 >> 6, dd0 = gn0 & 63;
        bf16x4 v;
#pragma unroll
        for (int rg = 0; rg < 4; ++rg) v[rg] = (__bf16)(acc[i][j][rg] * scale);
        *(bf16x4*)(Cout + (((size_t)bb * 8 + hh) * 2048 + tok) * 64 + dd0) = v;
      } else {
        const int gm0 = m0 + wm + i * 16 + qd * 4;      // token (4 consecutive)
        const int gn = n0 + wn + j * 16 + ln;           // e
        const int bb = gm0 >> 11, tok0 = gm0 & 2047;
        const int hh = gn >> 6, dd = gn & 63;
        bf16x4 v;
#pragma unroll
        for (int rg = 0; rg < 4; ++rg) v[rg] = (__bf16)acc[i][j][rg];
        *(bf16x4*)(Cout + (((size_t)bb * 8 + hh) * 64 + dd) * 2048 + tok0) = v;
      }
    }
}

// Fused Q/K/V projections: grid (64, 12) = 768 blocks -> 3 blocks/CU.
__global__ __launch_bounds__(256, 3) void proj_qkv(
    const __bf16* __restrict__ xb, const __bf16* __restrict__ cb,
    const __bf16* __restrict__ Wq, const __bf16* __restrict__ Wk,
    const __bf16* __restrict__ Wv, __bf16* __restrict__ Qw,
    __bf16* __restrict__ Kw, __bf16* __restrict__ Vtw) {
  __shared__ __align__(16) __bf16 As[128][72];  // 18432B
  __shared__ __align__(16) __bf16 Bs[128][72];  // 18432B -> 36.9KB
  const int m0 = blockIdx.x * 128;
  const int job = blockIdx.y >> 2;  // 0=Q, 1=K, 2=V
  const int n0 = (blockIdx.y & 3) * 128;
  if (job == 0)
    gemm_body<0>(xb, Wq, Qw, 512, QSCALE, m0, n0, As, Bs);
  else if (job == 1)
    gemm_body<0>(cb, Wk, Kw, 768, 1.0f, m0, n0, As, Bs);
  else
    gemm_body<1>(cb, Wv, Vtw, 768, 1.0f, m0, n0, As, Bs);
}

// ---------------------------------------------------------------------------
// Final GEMM: out = ((O0+O1)/(l0+l1)) Wo^T + bo, fp32.  64x128 tile, BK=64,
// register-prefetch pipeline, grid (128,4)=512.  inv(l) hoisted.
// ---------------------------------------------------------------------------
__global__ __launch_bounds__(256) void gemm_out(
    const __bf16* __restrict__ O0, const __bf16* __restrict__ O1,
    const float* __restrict__ lbuf,  // [2][32][2048]
    const __bf16* __restrict__ B,    // Wo bf16 [512 x 512]
    float* __restrict__ C, const float* __restrict__ bias) {
  const int m0 = blockIdx.x * 64;
  const int n0 = blockIdx.y * 128;
  const int t = threadIdx.x;
  const int w = t >> 6;
  const int lane = t & 63;
  const int ln = lane & 15;
  const int qd = lane >> 4;
  const int wm = (w >> 1) * 32;
  const int wn = (w & 1) * 64;

  __shared__ __align__(16) __bf16 As[64][72];   //  9216B
  __shared__ __align__(16) __bf16 Bs[128][72];  // 18432B -> 27.6KB

  f32x4 zero4 = {0.f, 0.f, 0.f, 0.f};
  f32x4 acc[2][4];
#pragma unroll
  for (int i = 0; i < 2; ++i)
#pragma unroll
    for (int j = 0; j < 4; ++j) acc[i][j] = zero4;

  const int r0 = t >> 2;        // 0..63
  const int c0 = (t & 3) * 16;  // 0/16/32/48
  const int gm_s = m0 + r0;
  const int bidx = gm_s >> 11, tok_s = gm_s & 2047;
  const size_t aoff = (size_t)gm_s * 512 + c0;
  const __bf16* gB0 = B + (size_t)(n0 + r0) * 512 + c0;
  const __bf16* gB1 = B + (size_t)(n0 + r0 + 64) * 512 + c0;

  float inv[8];
#pragma unroll
  for (int hh = 0; hh < 8; ++hh) {
    const float l0 = lbuf[((size_t)bidx * 8 + hh) * 2048 + tok_s];
    const float l1 = lbuf[65536 + ((size_t)bidx * 8 + hh) * 2048 + tok_s];
    inv[hh] = 1.0f / (l0 + l1);
  }

  // prologue: load tile 0
  uint4 o00 = *(const uint4*)(O0 + aoff), o01 = *(const uint4*)(O0 + aoff + 8);
  uint4 o10 = *(const uint4*)(O1 + aoff), o11 = *(const uint4*)(O1 + aoff + 8);
  uint4 b00 = *(const uint4*)gB0, b01 = *(const uint4*)(gB0 + 8);
  uint4 b10 = *(const uint4*)gB1, b11 = *(const uint4*)(gB1 + 8);

  for (int kc = 0; kc < 512; kc += 64) {
    const float iv = inv[kc >> 6];
    union { bf16x8 v; uint4 u; } u0, u1, r0v, r1v;
    u0.u = o00; u1.u = o10;
#pragma unroll
    for (int e = 0; e < 8; ++e)
      r0v.v[e] = (__bf16)(((float)u0.v[e] + (float)u1.v[e]) * iv);
    u0.u = o01; u1.u = o11;
#pragma unroll
    for (int e = 0; e < 8; ++e)
      r1v.v[e] = (__bf16)(((float)u0.v[e] + (float)u1.v[e]) * iv);
    __syncthreads();
    *(uint4*)&As[r0][c0] = r0v.u;
    *(uint4*)&As[r0][c0 + 8] = r1v.u;
    *(uint4*)&Bs[r0][c0] = b00;       *(uint4*)&Bs[r0][c0 + 8] = b01;
    *(uint4*)&Bs[r0 + 64][c0] = b10;  *(uint4*)&Bs[r0 + 64][c0 + 8] = b11;
    __syncthreads();
    if (kc + 64 < 512) {
      o00 = *(const uint4*)(O0 + aoff + kc + 64);
      o01 = *(const uint4*)(O0 + aoff + kc + 72);
      o10 = *(const uint4*)(O1 + aoff + kc + 64);
      o11 = *(const uint4*)(O1 + aoff + kc + 72);
      b00 = *(const uint4*)(gB0 + kc + 64);
      b01 = *(const uint4*)(gB0 + kc + 72);
      b10 = *(const uint4*)(gB1 + kc + 64);
      b11 = *(const uint4*)(gB1 + kc + 72);
    }
#pragma unroll
    for (int kst = 0; kst < 2; ++kst) {
      bf16x8 af[2], bfr[4];
#pragma unroll
      for (int i = 0; i < 2; ++i)
        af[i] = *(const bf16x8*)&As[wm + i * 16 + ln][kst * 32 + qd * 8];
#pragma unroll
      for (int j = 0; j < 4; ++j)
        bfr[j] = *(const bf16x8*)&Bs[wn + j * 16 + ln][kst * 32 + qd * 8];
#pragma unroll
      for (int i = 0; i < 2; ++i)
#pragma unroll
        for (int j = 0; j < 4; ++j)
          acc[i][j] = mfma32(bfr[j], af[i], acc[i][j]);  // e->(qd,rg)
    }
  }

#pragma unroll
  for (int i = 0; i < 2; ++i)
#pragma unroll
    for (int j = 0; j < 4; ++j) {
      const int gm = m0 + wm + i * 16 + ln;
      const int gn0 = n0 + wn + j * 16 + qd * 4;
      f32x4 bi = *(const f32x4*)&bias[gn0];
      f32x4 v = acc[i][j] + bi;
      *(f32x4*)&C[(size_t)gm * 512 + gn0] = v;
    }
}

// ---------------------------------------------------------------------------
// Flash attention: S^T trick, raw-exp2 max-free softmax, split-K=2, Q in
// regs, sigma-permuted K rows -> x32 PV, ones-x32 l row-sum.
// R15: BQ=256 with 512-thread blocks (8 waves), grid (8,32,2) -> 2 blocks/CU.
// R16: register-prefetch of next K/V tile + setprio around MFMA clusters.
// R18: LDS double-buffer Ks[2]/Vs[2] (71.7KB/block, 2 blocks/CU = 143KB),
//      SINGLE barrier per tile: ds_write of tile it+1 -> buf[p^1] overlaps
//      the MFMAs reading buf[p]; global prefetch issued a full tile ahead.
// ---------------------------------------------------------------------------
__global__ __launch_bounds__(512, 4) void attn_kernel(
    const __bf16* __restrict__ Q,   // [BH][2048][64], pre-scaled by QSCALE
    const __bf16* __restrict__ K,   // [BH][2048][64]
    const __bf16* __restrict__ Vt,  // [BH][64][2048]
    __bf16* __restrict__ Oh,        // [2][B][2048][512] unnormalized
    float* __restrict__ lbuf) {     // [2][BH][2048]
  const int S = 2048;
  const int qt = blockIdx.x;  // 8 Q tiles of 256 rows
  const int bh = blockIdx.y;
  const int sp = blockIdx.z;
  const int b = bh >> 3, h = bh & 7;
  const int t = threadIdx.x;
  const int w = t >> 6;       // 0..7: wave owns Q rows qt*256 + w*32 ..
  const int lane = t & 63;
  const int ln = lane & 15;
  const int qd = lane >> 4;

  __shared__ __align__(16) __bf16 Ks[2][128][72];   // 36864B
  __shared__ __align__(16) __bf16 Vs[2][64][136];   // 34816B  total 71680B

  bf16x8 bq[2][2];  // [mt][kst]
  {
    const __bf16* qb =
        Q + ((size_t)bh * S + qt * 256 + w * 32 + ln) * 64 + qd * 8;
#pragma unroll
    for (int mt = 0; mt < 2; ++mt)
#pragma unroll
      for (int kst = 0; kst < 2; ++kst)
        bq[mt][kst] = *(const bf16x8*)(qb + mt * 1024 + kst * 32);
  }

  f32x4 zero4 = {0.f, 0.f, 0.f, 0.f};
  f32x4 o[2][4];
  f32x4 o_l[2];
#pragma unroll
  for (int mt = 0; mt < 2; ++mt) {
#pragma unroll
    for (int i = 0; i < 4; ++i) o[mt][i] = zero4;
    o_l[mt] = zero4;
  }
  bf16x8 ones8;
  {
    union { unsigned short u[8]; bf16x8 v; } U;
#pragma unroll
    for (int e = 0; e < 8; ++e) U.u[e] = 0x3F80;  // bf16 1.0
    ones8 = U.v;
  }

  // K staging: 512 threads, token row kr = t>>2 (0..127), 16 cols each
  const int kr = t >> 2, kc0 = (t & 3) * 16;
  // sigma: token v -> row 16*((v>>2)&1) + 4*(v>>3) + (v&3) within 32-chunk
  const int krow =
      (kr & ~31) | ((kr & 4) << 2) | (((kr >> 3) & 3) << 2) | (kr & 3);
  // V staging: d-row vd = t>>3 (0..63), 16 tokens each
  const int vd = t >> 3, vtok0 = (t & 7) * 16;
  const int kt0 = sp * 8;

  // Hoisted global staging bases (advance by constants per tile).
  const __bf16* gKbase = K + ((size_t)bh * S + kt0 * 128 + kr) * 64 + kc0;
  const __bf16* gVbase = Vt + ((size_t)bh * 64 + vd) * S + kt0 * 128 + vtok0;

  // prologue: tile 0 -> regs -> LDS buf 0; issue tile 1 loads; one barrier.
  {
    uint4 kv0 = ((const uint4*)gKbase)[0], kv1 = ((const uint4*)gKbase)[1];
    uint4 vv0 = ((const uint4*)gVbase)[0], vv1 = ((const uint4*)gVbase)[1];
    uint4* dK = (uint4*)&Ks[0][krow][kc0];
    dK[0] = kv0; dK[1] = kv1;
    uint4* dV = (uint4*)&Vs[0][vd][vtok0];
    dV[0] = vv0; dV[1] = vv1;
  }
  uint4 kv0 = ((const uint4*)(gKbase + 8192))[0];
  uint4 kv1 = ((const uint4*)(gKbase + 8192))[1];
  uint4 vv0 = ((const uint4*)(gVbase + 128))[0];
  uint4 vv1 = ((const uint4*)(gVbase + 128))[1];
  __syncthreads();

  int p = 0;
  for (int it = 0; it < 8; ++it) {
    // stage tile it+1 into buf[p^1] (overlaps with compute on buf[p]);
    // issue global loads for tile it+2 (a full iteration of latency cover).
    if (it + 1 < 8) {
      uint4* dK = (uint4*)&Ks[p ^ 1][krow][kc0];
      dK[0] = kv0; dK[1] = kv1;
      uint4* dV = (uint4*)&Vs[p ^ 1][vd][vtok0];
      dV[0] = vv0; dV[1] = vv1;
      if (it + 2 < 8) {
        const uint4* gK = (const uint4*)(gKbase + (size_t)(it + 2) * 8192);
        const uint4* gV = (const uint4*)(gVbase + (size_t)(it + 2) * 128);
        kv0 = gK[0]; kv1 = gK[1];
        vv0 = gV[0]; vv1 = gV[1];
      }
    }

    const __bf16 (*Ksp)[72] = Ks[p];
    const __bf16 (*Vsp)[136] = Vs[p];

    // per 32-token chunk c: QK (2 tiles) -> exp2 -> x32 PV + ones row-sum
#pragma unroll
    for (int c = 0; c < 4; ++c) {
      f32x4 s[2][2];  // [e][mt]
      s[0][0] = zero4; s[0][1] = zero4; s[1][0] = zero4; s[1][1] = zero4;
      __builtin_amdgcn_s_setprio(1);
#pragma unroll
      for (int e = 0; e < 2; ++e) {
        const int nt = c * 2 + e;
#pragma unroll
        for (int kst = 0; kst < 2; ++kst) {
          bf16x8 ak = *(const bf16x8*)&Ksp[nt * 16 + ln][kst * 32 + qd * 8];
          s[e][0] = mfma32(ak, bq[0][kst], s[e][0]);
          s[e][1] = mfma32(ak, bq[1][kst], s[e][1]);
        }
      }
      __builtin_amdgcn_s_setprio(0);
#pragma unroll
      for (int e = 0; e < 2; ++e)
#pragma unroll
        for (int mt = 0; mt < 2; ++mt)
#pragma unroll
          for (int rg = 0; rg < 4; ++rg) s[e][mt][rg] = EXP2(s[e][mt][rg]);
      // pack P as x32 B-frag: lane holds tokens c*32 + qd*8 + j
      bf16x8 p2[2];
#pragma unroll
      for (int mt = 0; mt < 2; ++mt) {
#pragma unroll
        for (int rg = 0; rg < 4; ++rg) {
          p2[mt][rg] = (__bf16)s[0][mt][rg];
          p2[mt][rg + 4] = (__bf16)s[1][mt][rg];
        }
      }
      __builtin_amdgcn_s_setprio(1);
      o_l[0] = mfma32(ones8, p2[0], o_l[0]);
      o_l[1] = mfma32(ones8, p2[1], o_l[1]);
#pragma unroll
      for (int i = 0; i < 4; ++i) {
        bf16x8 av = *(const bf16x8*)&Vsp[i * 16 + ln][c * 32 + qd * 8];
        o[0][i] = mfma32(av, p2[0], o[0][i]);
        o[1][i] = mfma32(av, p2[1], o[1][i]);
      }
      __builtin_amdgcn_s_setprio(0);
    }

    __syncthreads();  // buf[p^1] fully staged; buf[p] reads complete
    p ^= 1;
  }

  // ---- epilogue: write UNNORMALIZED O + l (combine happens in gemm_out)
  __bf16* Osp = Oh + (size_t)sp * 8192 * 512;
#pragma unroll
  for (int mt = 0; mt < 2; ++mt) {
    const int tok = qt * 256 + w * 32 + mt * 16 + ln;
    if (qd == 0) lbuf[((size_t)sp * 32 + bh) * 2048 + tok] = o_l[mt][0];
#pragma unroll
    for (int i = 0; i < 4; ++i) {
      bf16x4 v;
#pragma unroll
      for (int rg = 0; rg < 4; ++rg) v[rg] = (__bf16)o[mt][i][rg];
      const int col = h * 64 + i * 16 + qd * 4;
      *(bf16x4*)&Osp[((size_t)b * S + tok) * 512 + col] = v;
    }
  }
}

// ---------------------------------------------------------------------------
extern "C" void kernel_launch(void* const* d_in, const int* in_sizes, int n_in,
                              void* d_out, int out_size, void* d_ws,
                              size_t ws_size, hipStream_t stream) {
  const float* x = (const float*)d_in[0];
  const float* ctx = (const float*)d_in[1];
  const float* Wq = (const float*)d_in[2];
  const float* Wk = (const float*)d_in[3];
  const float* Wv = (const float*)d_in[4];
  const float* Wo = (const float*)d_in[5];
  const float* bo = (const float*)d_in[6];

  char* p = (char*)d_ws;
  __bf16* xb = (__bf16*)p;   p += (size_t)8192 * 512 * 2;
  __bf16* cb = (__bf16*)p;   p += (size_t)8192 * 768 * 2;
  __bf16* wqb = (__bf16*)p;  p += (size_t)512 * 512 * 2;
  __bf16* wkb = (__bf16*)p;  p += (size_t)512 * 768 * 2;
  __bf16* wvb = (__bf16*)p;  p += (size_t)512 * 768 * 2;
  __bf16* wob = (__bf16*)p;  p += (size_t)512 * 512 * 2;
  __bf16* Qw = (__bf16*)p;   p += (size_t)8192 * 512 * 2;
  __bf16* Kw = (__bf16*)p;   p += (size_t)8192 * 512 * 2;
  __bf16* Vtw = (__bf16*)p;  p += (size_t)8192 * 512 * 2;
  __bf16* Oh = (__bf16*)p;   p += (size_t)2 * 8192 * 512 * 2;
  float* lbuf = (float*)p;   p += (size_t)2 * 32 * 2048 * 4;

  cast_all<<<2880, 256, 0, stream>>>(x, ctx, Wq, Wk, Wv, Wo, xb, cb, wqb, wkb,
                                     wvb, wob);

  dim3 gp(64, 12);
  proj_qkv<<<gp, 256, 0, stream>>>(xb, cb, wqb, wkb, wvb, Qw, Kw, Vtw);

  dim3 ga(8, 32, 2);
  attn_kernel<<<ga, 512, 0, stream>>>(Qw, Kw, Vtw, Oh, lbuf);

  dim3 go(128, 4);
  gemm_out<<<go, 256, 0, stream>>>(Oh, Oh + (size_t)8192 * 512, lbuf, wob,
                                   (float*)d_out, bo);
}

// Round 5
// 172.059 us; speedup vs baseline: 1.0201x; 1.0152x over previous
//
#include <hip/hip_runtime.h>
#include <hip/hip_bf16.h>
#include <math.h>

// ---------------------------------------------------------------------------
// CrossAttention on MI355X (gfx950), bf16 MFMA pipeline, round 20
// (resubmission of R19 — GPUAcquisitionTimeout, never measured).
//   cast_all: fp32 -> bf16 (BW-bound pass)
//   proj_qkv: 128x128, BK=64, coalesced 4-lane/row staging (R12/R14)
//   attn: R19 — WIDER WAVES: 4 waves x 64 Q rows (was 8 x 32). R18 counters
//         showed the LDS pipe ~73% busy (2048 ds_read_b128/block + 4.7M
//         conflict-cycles) vs MFMA 35%: each wave re-read the whole K/V tile
//         for only 32 Q rows. Doubling Q rows per wave halves LDS reads per
//         FLOP; ak/av frags now feed 4 mt instead of 2. Keeps R18 dbuf
//         single-barrier pipeline + R16 register prefetch + setprio.
//   gemm_out: 64x128, BK=64, combine in staging, inv hoisted (R12/R14)
// ---------------------------------------------------------------------------

typedef __bf16 bf16x8 __attribute__((ext_vector_type(8)));
typedef __bf16 bf16x4 __attribute__((ext_vector_type(4)));
typedef float f32x4 __attribute__((ext_vector_type(4)));

#define QSCALE 0.18033688011112042f  // 0.125 * log2(e)

#if __has_builtin(__builtin_amdgcn_exp2f)
#define EXP2(x) __builtin_amdgcn_exp2f(x)
#else
#define EXP2(x) exp2f(x)
#endif

__device__ __forceinline__ f32x4 mfma32(bf16x8 a, bf16x8 b, f32x4 c) {
  // 16x16x32: A[m=ln][k=qd*8+j], B[n=ln][k=qd*8+j].
  // D: A's m -> (qd*4+rg), B's n -> ln.
  return __builtin_amdgcn_mfma_f32_16x16x32_bf16(a, b, c, 0, 0, 0);
}

// ---------------------------------------------------------------------------
// fp32 -> bf16 cast of all inputs.
// ---------------------------------------------------------------------------
__global__ __launch_bounds__(256) void cast_all(
    const float* __restrict__ x, const float* __restrict__ ctx,
    const float* __restrict__ wq, const float* __restrict__ wk,
    const float* __restrict__ wv, const float* __restrict__ wo,
    __bf16* __restrict__ xb, __bf16* __restrict__ cb,
    __bf16* __restrict__ wqb, __bf16* __restrict__ wkb,
    __bf16* __restrict__ wvb, __bf16* __restrict__ wob) {
  const int B0 = 1048576;
  const int B1 = 2621440;
  const int B2 = 2686976;
  const int B3 = 2785280;
  const int B4 = 2883584;
  const int B5 = 2949120;
  for (int i = blockIdx.x * blockDim.x + threadIdx.x; i < B5;
       i += gridDim.x * blockDim.x) {
    const float* s;
    __bf16* d;
    int off;
    if (i < B0)      { s = x;   d = xb;  off = i; }
    else if (i < B1) { s = ctx; d = cb;  off = i - B0; }
    else if (i < B2) { s = wq;  d = wqb; off = i - B1; }
    else if (i < B3) { s = wk;  d = wkb; off = i - B2; }
    else if (i < B4) { s = wv;  d = wvb; off = i - B3; }
    else             { s = wo;  d = wob; off = i - B4; }
    float4 f = ((const float4*)s)[off];
    union { __bf16 b[4]; ushort4 u; } cv;
    cv.b[0] = (__bf16)f.x; cv.b[1] = (__bf16)f.y;
    cv.b[2] = (__bf16)f.z; cv.b[3] = (__bf16)f.w;
    ((ushort4*)d)[off] = cv.u;
  }
}

// ---------------------------------------------------------------------------
// 128x128 GEMM body, BK=64, register-prefetch pipeline, coalesced staging.
// MODE 0 (roles swapped): bf16 out [b,h,tok,d], 8B stores over d
// MODE 1 (natural roles): bf16 out [b,h,d,tok], 8B stores over tok
// ---------------------------------------------------------------------------
template <int MODE>
__device__ __forceinline__ void gemm_body(
    const __bf16* __restrict__ A, const __bf16* __restrict__ W,
    __bf16* __restrict__ Cout, int Kd, float scale, int m0, int n0,
    __bf16 (*As)[72], __bf16 (*Bs)[72]) {
  const int t = threadIdx.x;
  const int w = t >> 6;
  const int lane = t & 63;
  const int ln = lane & 15;
  const int qd = lane >> 4;
  const int wm = (w >> 1) * 64;
  const int wn = (w & 1) * 64;

  f32x4 zero4 = {0.f, 0.f, 0.f, 0.f};
  f32x4 acc[4][4];
#pragma unroll
  for (int i = 0; i < 4; ++i)
#pragma unroll
    for (int j = 0; j < 4; ++j) acc[i][j] = zero4;

  const int r0 = t >> 2;          // 0..63
  const int c0 = (t & 3) * 16;    // 0/16/32/48
  const __bf16* gA0 = A + (size_t)(m0 + r0) * Kd + c0;
  const __bf16* gA1 = A + (size_t)(m0 + r0 + 64) * Kd + c0;
  const __bf16* gB0 = W + (size_t)(n0 + r0) * Kd + c0;
  const __bf16* gB1 = W + (size_t)(n0 + r0 + 64) * Kd + c0;

  // prologue: load tile 0 into registers
  uint4 a00 = *(const uint4*)gA0, a01 = *(const uint4*)(gA0 + 8);
  uint4 a10 = *(const uint4*)gA1, a11 = *(const uint4*)(gA1 + 8);
  uint4 b00 = *(const uint4*)gB0, b01 = *(const uint4*)(gB0 + 8);
  uint4 b10 = *(const uint4*)gB1, b11 = *(const uint4*)(gB1 + 8);

  for (int kc = 0; kc < Kd; kc += 64) {
    __syncthreads();  // previous iteration's frag reads complete
    *(uint4*)&As[r0][c0] = a00;       *(uint4*)&As[r0][c0 + 8] = a01;
    *(uint4*)&As[r0 + 64][c0] = a10;  *(uint4*)&As[r0 + 64][c0 + 8] = a11;
    *(uint4*)&Bs[r0][c0] = b00;       *(uint4*)&Bs[r0][c0 + 8] = b01;
    *(uint4*)&Bs[r0 + 64][c0] = b10;  *(uint4*)&Bs[r0 + 64][c0 + 8] = b11;
    __syncthreads();  // LDS tile ready
    if (kc + 64 < Kd) {  // prefetch next tile: latency hidden behind MFMAs
      a00 = *(const uint4*)(gA0 + kc + 64);
      a01 = *(const uint4*)(gA0 + kc + 72);
      a10 = *(const uint4*)(gA1 + kc + 64);
      a11 = *(const uint4*)(gA1 + kc + 72);
      b00 = *(const uint4*)(gB0 + kc + 64);
      b01 = *(const uint4*)(gB0 + kc + 72);
      b10 = *(const uint4*)(gB1 + kc + 64);
      b11 = *(const uint4*)(gB1 + kc + 72);
    }
#pragma unroll
    for (int kst = 0; kst < 2; ++kst) {
      bf16x8 af[4], bfr[4];
#pragma unroll
      for (int i = 0; i < 4; ++i) {
        af[i] = *(const bf16x8*)&As[wm + i * 16 + ln][kst * 32 + qd * 8];
        bfr[i] = *(const bf16x8*)&Bs[wn + i * 16 + ln][kst * 32 + qd * 8];
      }
#pragma unroll
      for (int i = 0; i < 4; ++i)
#pragma unroll
        for (int j = 0; j < 4; ++j) {
          if (MODE == 1)
            acc[i][j] = mfma32(af[i], bfr[j], acc[i][j]);  // tok->(qd,rg)
          else
            acc[i][j] = mfma32(bfr[j], af[i], acc[i][j]);  // e->(qd,rg)
        }
    }
  }

#pragma unroll
  for (int i = 0; i < 4; ++i)
#pragma unroll
    for (int j = 0; j < 4; ++j) {
      if (MODE == 0) {
        const int gm = m0 + wm + i * 16 + ln;           // token
        const int gn0 = n0 + wn + j * 16 + qd * 4;      // e (4 consecutive)
        const int bb = gm >> 11, tok = gm & 2047;
        const int hh = gn0 >> 6, dd0 = gn0 & 63;
        bf16x4 v;
#pragma unroll
        for (int rg = 0; rg < 4; ++rg) v[rg] = (__bf16)(acc[i][j][rg] * scale);
        *(bf16x4*)(Cout + (((size_t)bb * 8 + hh) * 2048 + tok) * 64 + dd0) = v;
      } else {
        const int gm0 = m0 + wm + i * 16 + qd * 4;      // token (4 consecutive)
        const int gn = n0 + wn + j * 16 + ln;           // e
        const int bb = gm0 >> 11, tok0 = gm0 & 2047;
        const int hh = gn >> 6, dd = gn & 63;
        bf16x4 v;
#pragma unroll
        for (int rg = 0; rg < 4; ++rg) v[rg] = (__bf16)acc[i][j][rg];
        *(bf16x4*)(Cout + (((size_t)bb * 8 + hh) * 64 + dd) * 2048 + tok0) = v;
      }
    }
}

// Fused Q/K/V projections: grid (64, 12) = 768 blocks -> 3 blocks/CU.
__global__ __launch_bounds__(256, 3) void proj_qkv(
    const __bf16* __restrict__ xb, const __bf16* __restrict__ cb,
    const __bf16* __restrict__ Wq, const __bf16* __restrict__ Wk,
    const __bf16* __restrict__ Wv, __bf16* __restrict__ Qw,
    __bf16* __restrict__ Kw, __bf16* __restrict__ Vtw) {
  __shared__ __align__(16) __bf16 As[128][72];  // 18432B
  __shared__ __align__(16) __bf16 Bs[128][72];  // 18432B -> 36.9KB
  const int m0 = blockIdx.x * 128;
  const int job = blockIdx.y >> 2;  // 0=Q, 1=K, 2=V
  const int n0 = (blockIdx.y & 3) * 128;
  if (job == 0)
    gemm_body<0>(xb, Wq, Qw, 512, QSCALE, m0, n0, As, Bs);
  else if (job == 1)
    gemm_body<0>(cb, Wk, Kw, 768, 1.0f, m0, n0, As, Bs);
  else
    gemm_body<1>(cb, Wv, Vtw, 768, 1.0f, m0, n0, As, Bs);
}

// ---------------------------------------------------------------------------
// Final GEMM: out = ((O0+O1)/(l0+l1)) Wo^T + bo, fp32.  64x128 tile, BK=64,
// register-prefetch pipeline, grid (128,4)=512.  inv(l) hoisted.
// ---------------------------------------------------------------------------
__global__ __launch_bounds__(256) void gemm_out(
    const __bf16* __restrict__ O0, const __bf16* __restrict__ O1,
    const float* __restrict__ lbuf,  // [2][32][2048]
    const __bf16* __restrict__ B,    // Wo bf16 [512 x 512]
    float* __restrict__ C, const float* __restrict__ bias) {
  const int m0 = blockIdx.x * 64;
  const int n0 = blockIdx.y * 128;
  const int t = threadIdx.x;
  const int w = t >> 6;
  const int lane = t & 63;
  const int ln = lane & 15;
  const int qd = lane >> 4;
  const int wm = (w >> 1) * 32;
  const int wn = (w & 1) * 64;

  __shared__ __align__(16) __bf16 As[64][72];   //  9216B
  __shared__ __align__(16) __bf16 Bs[128][72];  // 18432B -> 27.6KB

  f32x4 zero4 = {0.f, 0.f, 0.f, 0.f};
  f32x4 acc[2][4];
#pragma unroll
  for (int i = 0; i < 2; ++i)
#pragma unroll
    for (int j = 0; j < 4; ++j) acc[i][j] = zero4;

  const int r0 = t >> 2;        // 0..63
  const int c0 = (t & 3) * 16;  // 0/16/32/48
  const int gm_s = m0 + r0;
  const int bidx = gm_s >> 11, tok_s = gm_s & 2047;
  const size_t aoff = (size_t)gm_s * 512 + c0;
  const __bf16* gB0 = B + (size_t)(n0 + r0) * 512 + c0;
  const __bf16* gB1 = B + (size_t)(n0 + r0 + 64) * 512 + c0;

  float inv[8];
#pragma unroll
  for (int hh = 0; hh < 8; ++hh) {
    const float l0 = lbuf[((size_t)bidx * 8 + hh) * 2048 + tok_s];
    const float l1 = lbuf[65536 + ((size_t)bidx * 8 + hh) * 2048 + tok_s];
    inv[hh] = 1.0f / (l0 + l1);
  }

  // prologue: load tile 0
  uint4 o00 = *(const uint4*)(O0 + aoff), o01 = *(const uint4*)(O0 + aoff + 8);
  uint4 o10 = *(const uint4*)(O1 + aoff), o11 = *(const uint4*)(O1 + aoff + 8);
  uint4 b00 = *(const uint4*)gB0, b01 = *(const uint4*)(gB0 + 8);
  uint4 b10 = *(const uint4*)gB1, b11 = *(const uint4*)(gB1 + 8);

  for (int kc = 0; kc < 512; kc += 64) {
    const float iv = inv[kc >> 6];
    union { bf16x8 v; uint4 u; } u0, u1, r0v, r1v;
    u0.u = o00; u1.u = o10;
#pragma unroll
    for (int e = 0; e < 8; ++e)
      r0v.v[e] = (__bf16)(((float)u0.v[e] + (float)u1.v[e]) * iv);
    u0.u = o01; u1.u = o11;
#pragma unroll
    for (int e = 0; e < 8; ++e)
      r1v.v[e] = (__bf16)(((float)u0.v[e] + (float)u1.v[e]) * iv);
    __syncthreads();
    *(uint4*)&As[r0][c0] = r0v.u;
    *(uint4*)&As[r0][c0 + 8] = r1v.u;
    *(uint4*)&Bs[r0][c0] = b00;       *(uint4*)&Bs[r0][c0 + 8] = b01;
    *(uint4*)&Bs[r0 + 64][c0] = b10;  *(uint4*)&Bs[r0 + 64][c0 + 8] = b11;
    __syncthreads();
    if (kc + 64 < 512) {
      o00 = *(const uint4*)(O0 + aoff + kc + 64);
      o01 = *(const uint4*)(O0 + aoff + kc + 72);
      o10 = *(const uint4*)(O1 + aoff + kc + 64);
      o11 = *(const uint4*)(O1 + aoff + kc + 72);
      b00 = *(const uint4*)(gB0 + kc + 64);
      b01 = *(const uint4*)(gB0 + kc + 72);
      b10 = *(const uint4*)(gB1 + kc + 64);
      b11 = *(const uint4*)(gB1 + kc + 72);
    }
#pragma unroll
    for (int kst = 0; kst < 2; ++kst) {
      bf16x8 af[2], bfr[4];
#pragma unroll
      for (int i = 0; i < 2; ++i)
        af[i] = *(const bf16x8*)&As[wm + i * 16 + ln][kst * 32 + qd * 8];
#pragma unroll
      for (int j = 0; j < 4; ++j)
        bfr[j] = *(const bf16x8*)&Bs[wn + j * 16 + ln][kst * 32 + qd * 8];
#pragma unroll
      for (int i = 0; i < 2; ++i)
#pragma unroll
        for (int j = 0; j < 4; ++j)
          acc[i][j] = mfma32(bfr[j], af[i], acc[i][j]);  // e->(qd,rg)
    }
  }

#pragma unroll
  for (int i = 0; i < 2; ++i)
#pragma unroll
    for (int j = 0; j < 4; ++j) {
      const int gm = m0 + wm + i * 16 + ln;
      const int gn0 = n0 + wn + j * 16 + qd * 4;
      f32x4 bi = *(const f32x4*)&bias[gn0];
      f32x4 v = acc[i][j] + bi;
      *(f32x4*)&C[(size_t)gm * 512 + gn0] = v;
    }
}

// ---------------------------------------------------------------------------
// Flash attention: S^T trick, raw-exp2 max-free softmax, split-K=2, Q in
// regs, sigma-permuted K rows -> x32 PV, ones-x32 l row-sum.
// R19: 4 waves x 64 Q ROWS each (256-thread blocks, BQ=256). R18's profile:
//      LDS pipe ~73% busy vs MfmaUtil 35% -> each 32-row wave re-read the
//      whole K/V tile. ak/av frags now amortize over 4 mt; LDS reads per
//      block halve (1024 vs 2048). VGPR ~200 fits 2 waves/SIMD.
//      Keeps dbuf single-barrier pipeline (R18) + reg prefetch (R16) +
//      setprio around MFMA clusters (T5). Grid (8,32,2)=512 -> 2 blocks/CU,
//      LDS 71.7KB x 2 = 143KB/CU.
// ---------------------------------------------------------------------------
__global__ __launch_bounds__(256, 2) void attn_kernel(
    const __bf16* __restrict__ Q,   // [BH][2048][64], pre-scaled by QSCALE
    const __bf16* __restrict__ K,   // [BH][2048][64]
    const __bf16* __restrict__ Vt,  // [BH][64][2048]
    __bf16* __restrict__ Oh,        // [2][B][2048][512] unnormalized
    float* __restrict__ lbuf) {     // [2][BH][2048]
  const int S = 2048;
  const int qt = blockIdx.x;  // 8 Q tiles of 256 rows
  const int bh = blockIdx.y;
  const int sp = blockIdx.z;
  const int b = bh >> 3, h = bh & 7;
  const int t = threadIdx.x;
  const int w = t >> 6;       // 0..3: wave owns Q rows qt*256 + w*64 ..
  const int lane = t & 63;
  const int ln = lane & 15;
  const int qd = lane >> 4;

  __shared__ __align__(16) __bf16 Ks[2][128][72];   // 36864B
  __shared__ __align__(16) __bf16 Vs[2][64][136];   // 34816B  total 71680B

  bf16x8 bq[4][2];  // [mt][kst] — 64 Q rows per wave
  {
    const __bf16* qb =
        Q + ((size_t)bh * S + qt * 256 + w * 64 + ln) * 64 + qd * 8;
#pragma unroll
    for (int mt = 0; mt < 4; ++mt)
#pragma unroll
      for (int kst = 0; kst < 2; ++kst)
        bq[mt][kst] = *(const bf16x8*)(qb + mt * 1024 + kst * 32);
  }

  f32x4 zero4 = {0.f, 0.f, 0.f, 0.f};
  f32x4 o[4][4];
  f32x4 o_l[4];
#pragma unroll
  for (int mt = 0; mt < 4; ++mt) {
#pragma unroll
    for (int i = 0; i < 4; ++i) o[mt][i] = zero4;
    o_l[mt] = zero4;
  }
  bf16x8 ones8;
  {
    union { unsigned short u[8]; bf16x8 v; } U;
#pragma unroll
    for (int e = 0; e < 8; ++e) U.u[e] = 0x3F80;  // bf16 1.0
    ones8 = U.v;
  }

  // K staging (256 threads): token row kr = t>>2 (0..63) and kr+64, 16 cols
  const int kr = t >> 2, kc0 = (t & 3) * 16;
  // sigma: token v -> row 16*((v>>2)&1) + 4*(v>>3) + (v&3) within 32-chunk
  const int krow =
      (kr & ~31) | ((kr & 4) << 2) | (((kr >> 3) & 3) << 2) | (kr & 3);
  // V staging: d-row vd = t>>3 (0..31) and vd+32, 16 tokens each
  const int vd = t >> 3, vtok0 = (t & 7) * 16;
  const int kt0 = sp * 8;

  // Hoisted global staging bases (advance by constants per tile).
  const __bf16* gK0 = K + ((size_t)bh * S + kt0 * 128 + kr) * 64 + kc0;
  const __bf16* gK1 = gK0 + 4096;   // row kr+64
  const __bf16* gV0 = Vt + ((size_t)bh * 64 + vd) * S + kt0 * 128 + vtok0;
  const __bf16* gV1 = gV0 + 65536;  // row vd+32

  // prologue: tile 0 -> LDS buf 0; prefetch tile 1 into regs; one barrier.
  {
    uint4 k00 = ((const uint4*)gK0)[0], k01 = ((const uint4*)gK0)[1];
    uint4 k10 = ((const uint4*)gK1)[0], k11 = ((const uint4*)gK1)[1];
    uint4 v00 = ((const uint4*)gV0)[0], v01 = ((const uint4*)gV0)[1];
    uint4 v10 = ((const uint4*)gV1)[0], v11 = ((const uint4*)gV1)[1];
    uint4* dK0 = (uint4*)&Ks[0][krow][kc0];      dK0[0] = k00; dK0[1] = k01;
    uint4* dK1 = (uint4*)&Ks[0][krow + 64][kc0]; dK1[0] = k10; dK1[1] = k11;
    uint4* dV0 = (uint4*)&Vs[0][vd][vtok0];      dV0[0] = v00; dV0[1] = v01;
    uint4* dV1 = (uint4*)&Vs[0][vd + 32][vtok0]; dV1[0] = v10; dV1[1] = v11;
  }
  uint4 pk00 = ((const uint4*)(gK0 + 8192))[0];
  uint4 pk01 = ((const uint4*)(gK0 + 8192))[1];
  uint4 pk10 = ((const uint4*)(gK1 + 8192))[0];
  uint4 pk11 = ((const uint4*)(gK1 + 8192))[1];
  uint4 pv00 = ((const uint4*)(gV0 + 128))[0];
  uint4 pv01 = ((const uint4*)(gV0 + 128))[1];
  uint4 pv10 = ((const uint4*)(gV1 + 128))[0];
  uint4 pv11 = ((const uint4*)(gV1 + 128))[1];
  __syncthreads();

  int p = 0;
  for (int it = 0; it < 8; ++it) {
    // stage tile it+1 into buf[p^1] (overlaps with compute on buf[p]);
    // issue global loads for tile it+2 (a full iteration of latency cover).
    if (it + 1 < 8) {
      uint4* dK0 = (uint4*)&Ks[p ^ 1][krow][kc0];
      dK0[0] = pk00; dK0[1] = pk01;
      uint4* dK1 = (uint4*)&Ks[p ^ 1][krow + 64][kc0];
      dK1[0] = pk10; dK1[1] = pk11;
      uint4* dV0 = (uint4*)&Vs[p ^ 1][vd][vtok0];
      dV0[0] = pv00; dV0[1] = pv01;
      uint4* dV1 = (uint4*)&Vs[p ^ 1][vd + 32][vtok0];
      dV1[0] = pv10; dV1[1] = pv11;
      if (it + 2 < 8) {
        const __bf16* nK0 = gK0 + (size_t)(it + 2) * 8192;
        const __bf16* nK1 = gK1 + (size_t)(it + 2) * 8192;
        const __bf16* nV0 = gV0 + (size_t)(it + 2) * 128;
        const __bf16* nV1 = gV1 + (size_t)(it + 2) * 128;
        pk00 = ((const uint4*)nK0)[0]; pk01 = ((const uint4*)nK0)[1];
        pk10 = ((const uint4*)nK1)[0]; pk11 = ((const uint4*)nK1)[1];
        pv00 = ((const uint4*)nV0)[0]; pv01 = ((const uint4*)nV0)[1];
        pv10 = ((const uint4*)nV1)[0]; pv11 = ((const uint4*)nV1)[1];
      }
    }

    const __bf16 (*Ksp)[72] = Ks[p];
    const __bf16 (*Vsp)[136] = Vs[p];

    // per 32-token chunk c: load ak/av frags ONCE, feed all 4 mt
#pragma unroll
    for (int c = 0; c < 4; ++c) {
      bf16x8 ak[2][2];  // [e][kst]
#pragma unroll
      for (int e = 0; e < 2; ++e)
#pragma unroll
        for (int kst = 0; kst < 2; ++kst)
          ak[e][kst] =
              *(const bf16x8*)&Ksp[(c * 2 + e) * 16 + ln][kst * 32 + qd * 8];
      bf16x8 av[4];
#pragma unroll
      for (int i = 0; i < 4; ++i)
        av[i] = *(const bf16x8*)&Vsp[i * 16 + ln][c * 32 + qd * 8];

#pragma unroll
      for (int mt = 0; mt < 4; ++mt) {
        f32x4 s0 = zero4, s1 = zero4;
        __builtin_amdgcn_s_setprio(1);
#pragma unroll
        for (int kst = 0; kst < 2; ++kst) {
          s0 = mfma32(ak[0][kst], bq[mt][kst], s0);
          s1 = mfma32(ak[1][kst], bq[mt][kst], s1);
        }
        __builtin_amdgcn_s_setprio(0);
#pragma unroll
        for (int rg = 0; rg < 4; ++rg) {
          s0[rg] = EXP2(s0[rg]);
          s1[rg] = EXP2(s1[rg]);
        }
        bf16x8 p2;  // P as x32 B-frag: lane holds tokens c*32 + qd*8 + j
#pragma unroll
        for (int rg = 0; rg < 4; ++rg) {
          p2[rg] = (__bf16)s0[rg];
          p2[rg + 4] = (__bf16)s1[rg];
        }
        __builtin_amdgcn_s_setprio(1);
        o_l[mt] = mfma32(ones8, p2, o_l[mt]);
#pragma unroll
        for (int i = 0; i < 4; ++i)
          o[mt][i] = mfma32(av[i], p2, o[mt][i]);
        __builtin_amdgcn_s_setprio(0);
      }
    }

    __syncthreads();  // buf[p^1] fully staged; buf[p] reads complete
    p ^= 1;
  }

  // ---- epilogue: write UNNORMALIZED O + l (combine happens in gemm_out)
  __bf16* Osp = Oh + (size_t)sp * 8192 * 512;
#pragma unroll
  for (int mt = 0; mt < 4; ++mt) {
    const int tok = qt * 256 + w * 64 + mt * 16 + ln;
    if (qd == 0) lbuf[((size_t)sp * 32 + bh) * 2048 + tok] = o_l[mt][0];
#pragma unroll
    for (int i = 0; i < 4; ++i) {
      bf16x4 v;
#pragma unroll
      for (int rg = 0; rg < 4; ++rg) v[rg] = (__bf16)o[mt][i][rg];
      const int col = h * 64 + i * 16 + qd * 4;
      *(bf16x4*)&Osp[((size_t)b * S + tok) * 512 + col] = v;
    }
  }
}

// ---------------------------------------------------------------------------
extern "C" void kernel_launch(void* const* d_in, const int* in_sizes, int n_in,
                              void* d_out, int out_size, void* d_ws,
                              size_t ws_size, hipStream_t stream) {
  const float* x = (const float*)d_in[0];
  const float* ctx = (const float*)d_in[1];
  const float* Wq = (const float*)d_in[2];
  const float* Wk = (const float*)d_in[3];
  const float* Wv = (const float*)d_in[4];
  const float* Wo = (const float*)d_in[5];
  const float* bo = (const float*)d_in[6];

  char* p = (char*)d_ws;
  __bf16* xb = (__bf16*)p;   p += (size_t)8192 * 512 * 2;
  __bf16* cb = (__bf16*)p;   p += (size_t)8192 * 768 * 2;
  __bf16* wqb = (__bf16*)p;  p += (size_t)512 * 512 * 2;
  __bf16* wkb = (__bf16*)p;  p += (size_t)512 * 768 * 2;
  __bf16* wvb = (__bf16*)p;  p += (size_t)512 * 768 * 2;
  __bf16* wob = (__bf16*)p;  p += (size_t)512 * 512 * 2;
  __bf16* Qw = (__bf16*)p;   p += (size_t)8192 * 512 * 2;
  __bf16* Kw = (__bf16*)p;   p += (size_t)8192 * 512 * 2;
  __bf16* Vtw = (__bf16*)p;  p += (size_t)8192 * 512 * 2;
  __bf16* Oh = (__bf16*)p;   p += (size_t)2 * 8192 * 512 * 2;
  float* lbuf = (float*)p;   p += (size_t)2 * 32 * 2048 * 4;

  cast_all<<<2880, 256, 0, stream>>>(x, ctx, Wq, Wk, Wv, Wo, xb, cb, wqb, wkb,
                                     wvb, wob);

  dim3 gp(64, 12);
  proj_qkv<<<gp, 256, 0, stream>>>(xb, cb, wqb, wkb, wvb, Qw, Kw, Vtw);

  dim3 ga(8, 32, 2);
  attn_kernel<<<ga, 256, 0, stream>>>(Qw, Kw, Vtw, Oh, lbuf);

  dim3 go(128, 4);
  gemm_out<<<go, 256, 0, stream>>>(Oh, Oh + (size_t)8192 * 512, lbuf, wob,
                                   (float*)d_out, bo);
}